// Round 5
// baseline (2959.040 us; speedup 1.0000x reference)
//
#include <hip/hip_runtime.h>
#include <float.h>

#define N_TOK 262144
#define N_E   1024
#define E_DIM 64
#define BETA  0.25f
#define TM    64     // tokens per block
#define BLK   256    // threads per block

// ---------------------------------------------------------------------------
// Bit-exact replica of numpy f32 sum of squares over 64 elements, streaming
// form (no 64-element local array -> no spill pressure). numpy reduce:
//   out = q0 + pairwise_sum(q[1:], 63)  with the 8-accumulator scheme:
//   r[t]=b[t]; for blk=8..48: r[t]+=b[blk+t];
//   res=((r0+r1)+(r2+r3))+((r4+r5)+(r6+r7)); res+=b[56..62] sequentially.
// All products/sums individually rounded -> __fmul_rn/__fadd_rn, no fma.
// DO NOT change the op order: index bit-exactness depends on it.
// ---------------------------------------------------------------------------
template <typename F>
__device__ __forceinline__ float np_sumsq64_f(F get)
{
    float r[8];
#pragma unroll
    for (int t = 0; t < 8; ++t) {
        float e = get(1 + t);
        r[t] = __fmul_rn(e, e);
    }
#pragma unroll
    for (int blk = 8; blk < 56; blk += 8) {
#pragma unroll
        for (int t = 0; t < 8; ++t) {
            float e = get(1 + blk + t);
            r[t] = __fadd_rn(r[t], __fmul_rn(e, e));
        }
    }
    float tA  = __fadd_rn(__fadd_rn(r[0], r[1]), __fadd_rn(r[2], r[3]));
    float tB  = __fadd_rn(__fadd_rn(r[4], r[5]), __fadd_rn(r[6], r[7]));
    float res = __fadd_rn(tA, tB);
#pragma unroll
    for (int k = 57; k < 64; ++k) {
        float e = get(k);
        res = __fadd_rn(res, __fmul_rn(e, e));
    }
    float e0 = get(0);
    return __fadd_rn(__fmul_rn(e0, e0), res);
}

// ---------------------------------------------------------------------------
// Prologue: scn[j] = np-f32 ||cb[j]||^2; zero the loss slot (harness does not
// re-poison d_out between replays; ordered before vq_main on the stream).
// ---------------------------------------------------------------------------
__global__ __launch_bounds__(256) void vq_prep(const float* __restrict__ cb,
                                               float* __restrict__ scn,
                                               float* __restrict__ loss_slot)
{
    int j = blockIdx.x * 256 + threadIdx.x;
    if (j < N_E) {
        const float* c = cb + (size_t)j * E_DIM;
        scn[j] = np_sumsq64_f([&](int k) { return c[k]; });
    }
    if (blockIdx.x == 0 && threadIdx.x == 0) *loss_slot = 0.f;
}

// ---------------------------------------------------------------------------
// Fused GEMM-argmin. Block: TM=64 tokens. Thread (t): token-group g_m=t&15
// (tokens 4*g_m..+3), j-group g_j=t>>4 (j = jc*64 + 4*g_j + 0..3).
// x-tile transposed in LDS At[k][token] (pad 68: b128 reads 2-way==free).
// B (codebook) read from global, L1/L2-hot, compile-time offsets.
// Each output's k-chain: single fmaf accumulator, k ascending (bit-exact,
// same as the passing round-3 kernel). Argmin: per-thread strict < ascending
// j, then lexicographic (d, idx) reduce == numpy first-occurrence.
// ---------------------------------------------------------------------------
__global__ __launch_bounds__(256, 4)
void vq_main(const float* __restrict__ x,
             const float* __restrict__ cb,
             const float* __restrict__ scn,
             float* __restrict__ xq_out,
             float* __restrict__ loss_out,
             float* __restrict__ idx_out)
{
    __shared__ __align__(16) float At[E_DIM][TM + 4];  // [k][token], stride 68
    __shared__ __align__(16) float scns[N_E];
    __shared__ __align__(16) float sxs[TM];
    __shared__ float wred_d[4 * TM];
    __shared__ int   wred_i[4 * TM];
    __shared__ int   ibuf[TM];
    __shared__ float red[4];

    const int t  = threadIdx.x;
    const int T0 = blockIdx.x * TM;

    // ---- stage x tile transposed: thread t loads row t/4, quarter t%4 ----
    {
        const int r = t >> 2, s = t & 3;
        const float* xr = x + (size_t)(T0 + r) * E_DIM + s * 16;
        float4 v[4];
#pragma unroll
        for (int i = 0; i < 4; ++i) v[i] = *(const float4*)(xr + 4 * i);
#pragma unroll
        for (int i = 0; i < 16; ++i)
            At[s * 16 + i][r] = ((const float*)v)[i];
    }
    // ---- stage scn (1024 floats) ----
    {
        float4 v = *(const float4*)(scn + t * 4);
        *(float4*)(&scns[t * 4]) = v;
    }
    __syncthreads();

    // ---- sx per token, numpy order, streamed from LDS column (wave 0) ----
    if (t < TM) {
        sxs[t] = np_sumsq64_f([&](int k) { return At[k][t]; });
    }
    __syncthreads();

    const int g_m = t & 15;
    const int g_j = t >> 4;

    float sx[4];
    {
        float4 s4 = *(const float4*)(&sxs[4 * g_m]);
        sx[0] = s4.x; sx[1] = s4.y; sx[2] = s4.z; sx[3] = s4.w;
    }

    float dmin[4] = {FLT_MAX, FLT_MAX, FLT_MAX, FLT_MAX};
    int   imin[4] = {0, 0, 0, 0};

    const float* cbp = cb + (size_t)(4 * g_j) * E_DIM;   // rows j0..j0+3
    for (int jc = 0; jc < 16; ++jc) {
        const int j0 = jc * 64 + 4 * g_j;
        float m[4][4];                                   // [token][j]
#pragma unroll
        for (int a = 0; a < 4; ++a)
#pragma unroll
            for (int b = 0; b < 4; ++b) m[a][b] = 0.f;

#pragma unroll
        for (int k0 = 0; k0 < E_DIM; k0 += 4) {
            float bv[4][4];                              // [jl][kk]
#pragma unroll
            for (int jl = 0; jl < 4; ++jl) {
                float4 q = *(const float4*)(cbp + jl * E_DIM + k0);
                bv[jl][0] = q.x; bv[jl][1] = q.y; bv[jl][2] = q.z; bv[jl][3] = q.w;
            }
            float av[4][4];                              // [kk][token]
#pragma unroll
            for (int kk = 0; kk < 4; ++kk) {
                float4 q = *(const float4*)(&At[k0 + kk][4 * g_m]);
                av[kk][0] = q.x; av[kk][1] = q.y; av[kk][2] = q.z; av[kk][3] = q.w;
            }
            // k outermost: each m[tm][jl] advances one fmaf per k, ascending
#pragma unroll
            for (int kk = 0; kk < 4; ++kk)
#pragma unroll
                for (int tm = 0; tm < 4; ++tm)
#pragma unroll
                    for (int jl = 0; jl < 4; ++jl)
                        m[tm][jl] = fmaf(av[kk][tm], bv[jl][kk], m[tm][jl]);
        }

        float4 sc4 = *(const float4*)(&scns[j0]);
        float scv[4] = {sc4.x, sc4.y, sc4.z, sc4.w};
#pragma unroll
        for (int tm = 0; tm < 4; ++tm)
#pragma unroll
            for (int jl = 0; jl < 4; ++jl) {             // jl ascending = j asc
                float d = __fsub_rn(__fadd_rn(sx[tm], scv[jl]),
                                    __fmul_rn(2.0f, m[tm][jl]));
                if (d < dmin[tm]) { dmin[tm] = d; imin[tm] = j0 + jl; }
            }
        cbp += 64 * E_DIM;
    }

    // ---- cross-thread argmin: lexicographic (d, idx) ----
    const int wave = t >> 6;
#pragma unroll
    for (int tm = 0; tm < 4; ++tm) {
        float d = dmin[tm]; int i = imin[tm];
#pragma unroll
        for (int off = 16; off <= 32; off <<= 1) {
            float od = __shfl_xor(d, off, 64);
            int   oi = __shfl_xor(i, off, 64);
            if (od < d || (od == d && oi < i)) { d = od; i = oi; }
        }
        if ((t & 63) < 16) {
            wred_d[wave * TM + g_m * 4 + tm] = d;
            wred_i[wave * TM + g_m * 4 + tm] = i;
        }
    }
    __syncthreads();
    if (t < TM) {
        float d = wred_d[t]; int i = wred_i[t];
#pragma unroll
        for (int w = 1; w < 4; ++w) {
            float od = wred_d[w * TM + t]; int oi = wred_i[w * TM + t];
            if (od < d || (od == d && oi < i)) { d = od; i = oi; }
        }
        ibuf[t] = i;
        idx_out[T0 + t] = (float)i;                      // exact int in f32
    }
    __syncthreads();

    // ---- epilogue: gather winning rows (coalesced), fused loss ----
    float lsum = 0.f;
    {
        const int m_ = t >> 2, s = t & 3;
        const int ci = ibuf[m_];
        const float* crow = cb + (size_t)ci * E_DIM + s * 16;
        float*       qrow = xq_out + (size_t)(T0 + m_) * E_DIM + s * 16;
#pragma unroll
        for (int i = 0; i < 4; ++i) {
            float4 cv = *(const float4*)(crow + 4 * i);
            *(float4*)(qrow + 4 * i) = cv;               // fwd x_q_st == x_q
            float e;
            e = cv.x - At[s * 16 + 4 * i + 0][m_]; lsum = fmaf(e, e, lsum);
            e = cv.y - At[s * 16 + 4 * i + 1][m_]; lsum = fmaf(e, e, lsum);
            e = cv.z - At[s * 16 + 4 * i + 2][m_]; lsum = fmaf(e, e, lsum);
            e = cv.w - At[s * 16 + 4 * i + 3][m_]; lsum = fmaf(e, e, lsum);
        }
    }
    for (int off = 1; off < 64; off <<= 1) lsum += __shfl_xor(lsum, off, 64);
    if ((t & 63) == 0) red[t >> 6] = lsum;
    __syncthreads();
    if (t == 0) {
        float part = (red[0] + red[1]) + (red[2] + red[3]);
        const float scale = (1.0f + BETA) / ((float)N_TOK * (float)E_DIM);
        atomicAdd(loss_out, part * scale);
    }
}

extern "C" void kernel_launch(void* const* d_in, const int* in_sizes, int n_in,
                              void* d_out, int out_size, void* d_ws, size_t ws_size,
                              hipStream_t stream)
{
    const float* x  = (const float*)d_in[0];   // [262144, 64] f32
    const float* cb = (const float*)d_in[1];   // [1024, 64]   f32

    float* out  = (float*)d_out;
    float* xq   = out;                              // 262144*64 floats
    float* loss = out + (size_t)N_TOK * E_DIM;      // 1 float
    float* idx  = loss + 1;                         // 262144 floats

    float* scn = (float*)d_ws;                      // 1024 floats scratch

    vq_prep<<<N_E / 256, 256, 0, stream>>>(cb, scn, loss);
    vq_main<<<N_TOK / TM, BLK, 0, stream>>>(x, cb, scn, xq, loss, idx);
}

// Round 6
// 614.546 us; speedup vs baseline: 4.8150x; 4.8150x over previous
//
#include <hip/hip_runtime.h>
#include <float.h>

#define N_TOK 262144
#define N_E   1024
#define E_DIM 64
#define BETA  0.25f

// x-row lives in a 64-wide ext_vector: pure SSA value, constant-index
// subscripts only -> cannot be demoted to scratch (rounds 3/4/5 all
// pinned VGPR=52..64 with massive scratch traffic from float xr[64]).
typedef float f32x64 __attribute__((ext_vector_type(64)));

// ---------------------------------------------------------------------------
// Bit-exact replica of numpy f32 sum-of-squares over 64 elements.
// numpy reduce: out = q0 + pairwise_sum(q[1:], 63); pairwise (n=63):
//   r[t] = b[t] (t=0..7); for blk=8,16,..,48: r[t] += b[blk+t];
//   res = ((r0+r1)+(r2+r3))+((r4+r5)+(r6+r7)); res += b[56..62] seq.
// where b[i] = v[1+i]. All ops individually rounded (no FMA contraction).
// DO NOT change the op order: index bit-exactness depends on it.
// Takes the vector BY VALUE (no pointer escape).
// ---------------------------------------------------------------------------
__device__ __forceinline__ float np_sumsq64_v(f32x64 v)
{
    float r0 = __fmul_rn(v[1], v[1]);
    float r1 = __fmul_rn(v[2], v[2]);
    float r2 = __fmul_rn(v[3], v[3]);
    float r3 = __fmul_rn(v[4], v[4]);
    float r4 = __fmul_rn(v[5], v[5]);
    float r5 = __fmul_rn(v[6], v[6]);
    float r6 = __fmul_rn(v[7], v[7]);
    float r7 = __fmul_rn(v[8], v[8]);
#define VQ_ACC8(blk)                                                     \
    r0 = __fadd_rn(r0, __fmul_rn(v[1 + (blk) + 0], v[1 + (blk) + 0]));  \
    r1 = __fadd_rn(r1, __fmul_rn(v[1 + (blk) + 1], v[1 + (blk) + 1]));  \
    r2 = __fadd_rn(r2, __fmul_rn(v[1 + (blk) + 2], v[1 + (blk) + 2]));  \
    r3 = __fadd_rn(r3, __fmul_rn(v[1 + (blk) + 3], v[1 + (blk) + 3]));  \
    r4 = __fadd_rn(r4, __fmul_rn(v[1 + (blk) + 4], v[1 + (blk) + 4]));  \
    r5 = __fadd_rn(r5, __fmul_rn(v[1 + (blk) + 5], v[1 + (blk) + 5]));  \
    r6 = __fadd_rn(r6, __fmul_rn(v[1 + (blk) + 6], v[1 + (blk) + 6]));  \
    r7 = __fadd_rn(r7, __fmul_rn(v[1 + (blk) + 7], v[1 + (blk) + 7]))
    VQ_ACC8(8);
    VQ_ACC8(16);
    VQ_ACC8(24);
    VQ_ACC8(32);
    VQ_ACC8(40);
    VQ_ACC8(48);
#undef VQ_ACC8
    float tA  = __fadd_rn(__fadd_rn(r0, r1), __fadd_rn(r2, r3));
    float tB  = __fadd_rn(__fadd_rn(r4, r5), __fadd_rn(r6, r7));
    float res = __fadd_rn(tA, tB);
    res = __fadd_rn(res, __fmul_rn(v[57], v[57]));
    res = __fadd_rn(res, __fmul_rn(v[58], v[58]));
    res = __fadd_rn(res, __fmul_rn(v[59], v[59]));
    res = __fadd_rn(res, __fmul_rn(v[60], v[60]));
    res = __fadd_rn(res, __fmul_rn(v[61], v[61]));
    res = __fadd_rn(res, __fmul_rn(v[62], v[62]));
    res = __fadd_rn(res, __fmul_rn(v[63], v[63]));
    return __fadd_rn(__fmul_rn(v[0], v[0]), res);
}

// ---------------------------------------------------------------------------
// Prologue: scn[j] = np-f32 ||cb[j]||^2; zero the loss slot (harness does not
// re-poison d_out between replays; ordered before vq_main on the stream).
// ---------------------------------------------------------------------------
__global__ __launch_bounds__(256) void vq_prep(const float* __restrict__ cb,
                                               float* __restrict__ scn,
                                               float* __restrict__ loss_slot)
{
    int j = blockIdx.x * 256 + threadIdx.x;
    if (j < N_E) {
        const float* c = cb + (size_t)j * E_DIM;
        f32x64 cr;
#pragma unroll
        for (int k = 0; k < E_DIM; k += 4) {
            float4 v = *(const float4*)(c + k);
            cr[k] = v.x; cr[k + 1] = v.y; cr[k + 2] = v.z; cr[k + 3] = v.w;
        }
        scn[j] = np_sumsq64_v(cr);
    }
    if (blockIdx.x == 0 && threadIdx.x == 0) *loss_slot = 0.f;
}

// ---------------------------------------------------------------------------
// Main (round-3 structure, spill-proofed): one token/thread, x-row in a
// f32x64 SSA vector. Bit-exact np f32 distance:
//   m_j  : single-accumulator fmaf chain, k ascending (BLAS order)
//   d_j  = f32( f32(sx + scn_j) - f32(2*m_j) )
//   argmin: strict <, ascending j (numpy first-occurrence)
// Codebook addresses are wave-uniform -> scalar/broadcast loads, L2/L3-hot.
// ---------------------------------------------------------------------------
__global__ __launch_bounds__(256)
void vq_main(const float* __restrict__ x,
             const float* __restrict__ cb,
             const float* __restrict__ scn,
             float* __restrict__ xq_out,
             float* __restrict__ loss_out,
             float* __restrict__ idx_out)
{
    const int tok = blockIdx.x * blockDim.x + threadIdx.x;

    f32x64 xr;
    {
        const float* xrow = x + (size_t)tok * E_DIM;
#pragma unroll
        for (int k = 0; k < E_DIM; k += 4) {
            float4 v = *(const float4*)(xrow + k);
            xr[k] = v.x; xr[k + 1] = v.y; xr[k + 2] = v.z; xr[k + 3] = v.w;
        }
    }

    const float sx = np_sumsq64_v(xr);

    float dmin = FLT_MAX;
    int   imin = 0;

    for (int j = 0; j < N_E; j += 2) {
        const float* c0 = cb + (size_t)j * E_DIM;   // wave-uniform addresses
        const float* c1 = c0 + E_DIM;
        float m0 = 0.f, m1 = 0.f;                   // sequential k-chains
#pragma unroll
        for (int k = 0; k < E_DIM; ++k) {
            m0 = fmaf(xr[k], c0[k], m0);
            m1 = fmaf(xr[k], c1[k], m1);
        }
        float d0 = __fsub_rn(__fadd_rn(sx, scn[j    ]), __fmul_rn(2.0f, m0));
        float d1 = __fsub_rn(__fadd_rn(sx, scn[j + 1]), __fmul_rn(2.0f, m1));
        if (d0 < dmin) { dmin = d0; imin = j; }
        if (d1 < dmin) { dmin = d1; imin = j + 1; }
    }

    // Epilogue: gather winning codebook row (L2/L3-hot), fused loss.
    float lsum = 0.f;
    {
        const float* cmin = cb + (size_t)imin * E_DIM;  // per-lane address
        float*       xq   = xq_out + (size_t)tok * E_DIM;
#pragma unroll
        for (int k = 0; k < E_DIM; k += 4) {
            float4 cv = *(const float4*)(cmin + k);
            *(float4*)(xq + k) = cv;                    // fwd x_q_st == x_q
            float e0 = cv.x - xr[k    ];
            float e1 = cv.y - xr[k + 1];
            float e2 = cv.z - xr[k + 2];
            float e3 = cv.w - xr[k + 3];
            lsum = fmaf(e0, e0, lsum);
            lsum = fmaf(e1, e1, lsum);
            lsum = fmaf(e2, e2, lsum);
            lsum = fmaf(e3, e3, lsum);
        }
    }
    idx_out[tok] = (float)imin;   // exact integer in f32

    // Loss: 64-lane shuffle tree, cross-wave via LDS, one atomic per block.
    for (int m = 1; m < 64; m <<= 1) lsum += __shfl_xor(lsum, m, 64);
    __shared__ float red[4];
    const int lane = threadIdx.x & 63;
    const int wid  = threadIdx.x >> 6;
    if (lane == 0) red[wid] = lsum;
    __syncthreads();
    if (threadIdx.x == 0) {
        float part = red[0] + red[1] + red[2] + red[3];
        const float scale = (1.0f + BETA) / ((float)N_TOK * (float)E_DIM);
        atomicAdd(loss_out, part * scale);
    }
}

extern "C" void kernel_launch(void* const* d_in, const int* in_sizes, int n_in,
                              void* d_out, int out_size, void* d_ws, size_t ws_size,
                              hipStream_t stream)
{
    const float* x  = (const float*)d_in[0];   // [262144, 64] f32
    const float* cb = (const float*)d_in[1];   // [1024, 64]   f32

    float* out  = (float*)d_out;
    float* xq   = out;                              // 262144*64 floats
    float* loss = out + (size_t)N_TOK * E_DIM;      // 1 float
    float* idx  = loss + 1;                         // 262144 floats

    float* scn = (float*)d_ws;                      // 1024 floats scratch

    vq_prep<<<N_E / 256, 256, 0, stream>>>(cb, scn, loss);
    vq_main<<<N_TOK / 256, 256, 0, stream>>>(x, cb, scn, xq, loss, idx);
}